// Round 5
// baseline (530.112 us; speedup 1.0000x reference)
//
#include <hip/hip_runtime.h>
#include <hip/hip_bf16.h>

#define BB 2
#define NN 16384
#define KK 16
#define CC 256
#define NHH 4
#define HDD 64
#define BN (BB*NN)   // 32768

typedef __attribute__((ext_vector_type(8))) short short8;
typedef __attribute__((ext_vector_type(4))) float f32x4;

__device__ __forceinline__ float bf2f(unsigned short u) {
    union { unsigned u32; float f; } x; x.u32 = ((unsigned)u) << 16; return x.f;
}
__device__ __forceinline__ unsigned short f2bf(float f) {
    union { float f; unsigned u; } x; x.f = f;
    unsigned r = x.u + 0x7FFFu + ((x.u >> 16) & 1u);
    return (unsigned short)(r >> 16);
}

// ---------------------------------------------------------------------------
// Prep: WqaT = (Wq @ blockdiag(Wa1))^T, WkaT, WpeaT likewise; plain transposes
// WvT, Wp2T, WoT; b_u = bp2 @ blockdiag(Wa1) + tile(ba1). All bf16 except b_u.
// grid (256, 7), 256 threads.
// ---------------------------------------------------------------------------
__global__ __launch_bounds__(256) void prep_kernel(
    const float* __restrict__ Wq, const float* __restrict__ Wk,
    const float* __restrict__ Wv, const float* __restrict__ Wp2,
    const float* __restrict__ Wo, const float* __restrict__ Wa1,
    const float* __restrict__ bp2, const float* __restrict__ ba1,
    unsigned short* WqaT, unsigned short* WkaT, unsigned short* WvT,
    unsigned short* WpeaT, unsigned short* Wp2T, unsigned short* WoT,
    float* b_u)
{
    const int z = blockIdx.y;
    const int t = threadIdx.x;
    if (z < 3) {
        const float* W = (z == 0) ? Wq : (z == 1) ? Wk : Wp2;
        unsigned short* out = (z == 0) ? WqaT : (z == 1) ? WkaT : WpeaT;
        const int k = blockIdx.x;                 // row of W
        __shared__ float wrow[CC];
        __shared__ float a1[HDD * HDD];
        wrow[t] = W[k * CC + t];
        for (int i = t; i < HDD * HDD; i += 256) a1[i] = Wa1[i];
        __syncthreads();
        const int c = t;
        const int h0 = c & ~63;
        const int cl = c & 63;
        float s = 0.f;
        #pragma unroll 8
        for (int j = 0; j < HDD; ++j) s += wrow[h0 + j] * a1[j * HDD + cl];
        out[c * CC + k] = f2bf(s);
    } else if (z < 6) {
        const float* W = (z == 3) ? Wv : (z == 4) ? Wp2 : Wo;
        unsigned short* out = (z == 3) ? WvT : (z == 4) ? Wp2T : WoT;
        const int k = blockIdx.x;
        out[t * CC + k] = f2bf(W[k * CC + t]);
    } else {
        if (blockIdx.x != 0) return;
        __shared__ float a1[HDD * HDD];
        for (int i = t; i < HDD * HDD; i += 256) a1[i] = Wa1[i];
        __syncthreads();
        const int c = t;
        const int h0 = c & ~63;
        const int cl = c & 63;
        float s = ba1[cl];
        #pragma unroll 8
        for (int j = 0; j < HDD; ++j) s += bp2[h0 + j] * a1[j * HDD + cl];
        b_u[c] = s;
    }
}

// h (f32) -> hbf (bf16). grid 8192 x 256, 4 elems/thread.
__global__ __launch_bounds__(256) void h2bf_kernel(const float* __restrict__ h,
                                                   unsigned short* __restrict__ hbf)
{
    const int i = blockIdx.x * blockDim.x + threadIdx.x;
    const float4 v = ((const float4*)h)[i];
    ushort4 o;
    o.x = f2bf(v.x); o.y = f2bf(v.y); o.z = f2bf(v.z); o.w = f2bf(v.w);
    ((ushort4*)hbf)[i] = o;
}

// ---------------------------------------------------------------------------
// 64-row MFMA GEMM: D[m0:m0+64, 0:256] = A[m0:m0+64, :] @ B (B given as BT[col][k]).
// FINAL=false: 3 weight/dest pairs via blockIdx.y, bf16 out.
// FINAL=true : single, f32 out + bias.
// block 256 = 4 waves; wave w owns columns [64w, 64w+64).
// ---------------------------------------------------------------------------
template<bool FINAL>
__global__ __launch_bounds__(256) void gemm64_kernel(
    const unsigned short* __restrict__ A,
    const unsigned short* __restrict__ BT0, const unsigned short* __restrict__ BT1,
    const unsigned short* __restrict__ BT2,
    unsigned short* D0, unsigned short* D1, unsigned short* D2,
    float* Dout, const float* __restrict__ bias)
{
    const int m0 = blockIdx.x * 64;
    const unsigned short* BT;
    unsigned short* Dst = nullptr;
    if (!FINAL) {
        const int z = blockIdx.y;
        BT  = (z == 0) ? BT0 : (z == 1) ? BT1 : BT2;
        Dst = (z == 0) ? D0  : (z == 1) ? D1  : D2;
    } else {
        BT = BT0;
    }

    __shared__ __align__(16) unsigned short As[64 * 264];
    const int t = threadIdx.x;
    #pragma unroll
    for (int i = 0; i < 8; ++i) {
        const int flat = i * 2048 + t * 8;
        const int r = flat >> 8, c = flat & 255;
        short8 v = *(const short8*)(A + (size_t)(m0 + r) * CC + c);
        *(short8*)(&As[r * 264 + c]) = v;
    }
    __syncthreads();

    const int lane = t & 63, w = t >> 6;
    const int lr = lane & 15, lg = lane >> 4;

    f32x4 acc[4][4];
    #pragma unroll
    for (int mi = 0; mi < 4; ++mi)
        #pragma unroll
        for (int ni = 0; ni < 4; ++ni) acc[mi][ni] = (f32x4){0.f, 0.f, 0.f, 0.f};

    #pragma unroll
    for (int kk = 0; kk < 8; ++kk) {
        const int ko = kk * 32 + lg * 8;
        short8 a[4];
        #pragma unroll
        for (int mi = 0; mi < 4; ++mi)
            a[mi] = *(const short8*)(&As[(mi * 16 + lr) * 264 + ko]);
        #pragma unroll
        for (int ni = 0; ni < 4; ++ni) {
            const int col = w * 64 + ni * 16 + lr;
            short8 b = *(const short8*)(BT + (size_t)col * CC + ko);
            #pragma unroll
            for (int mi = 0; mi < 4; ++mi)
                acc[mi][ni] = __builtin_amdgcn_mfma_f32_16x16x32_bf16(a[mi], b, acc[mi][ni], 0, 0, 0);
        }
    }

    #pragma unroll
    for (int mi = 0; mi < 4; ++mi) {
        #pragma unroll
        for (int ni = 0; ni < 4; ++ni) {
            const int col = w * 64 + ni * 16 + lr;
            #pragma unroll
            for (int reg = 0; reg < 4; ++reg) {
                const int row = m0 + mi * 16 + lg * 4 + reg;
                const float v = acc[mi][ni][reg];
                if (FINAL) Dout[(size_t)row * CC + col] = v + bias[col];
                else       Dst[(size_t)row * CC + col] = f2bf(v);
            }
        }
    }
}

// ---------------------------------------------------------------------------
// Fused per-point attention. Block = 4 points x 16 neighbors = 64 rows,
// 256 threads (4 waves; wave w = head w).
// LDS = 38400 B; __launch_bounds__(256,3): r4 showed the 128-reg cap of
// 4 blocks/CU starves gather ILP (VGPR 64, VALUBusy down, dur up) -- 3
// blocks/CU with ~170 regs is the sweet spot.
// T14 issue-early/consume-late: KA gather (64 loads/lane) issued right after
// the nbr barrier, hidden under the hidden-MLP + U-GEMM MFMA loop; V gather
// issued after logits (KA regs dead), hidden under softmax barrier + hbar.
// ---------------------------------------------------------------------------
__global__ __launch_bounds__(256, 3) void fused_attn_kernel(
    const float* __restrict__ P, const int* __restrict__ idx,
    const float* __restrict__ Wp1, const float* __restrict__ bp1,
    const float* __restrict__ Wa2, const float* __restrict__ bp2,
    const unsigned short* __restrict__ QAbf, const unsigned short* __restrict__ KAbf,
    const unsigned short* __restrict__ Vbf,  const unsigned short* __restrict__ WpeaT,
    const unsigned short* __restrict__ Wp2T, const float* __restrict__ b_u,
    unsigned short* __restrict__ aggbf)
{
    const int pt0 = blockIdx.x * 4;
    const int b = pt0 >> 14;          // pt0 / NN
    const int n0 = pt0 & (NN - 1);
    const int t = threadIdx.x;
    const int lane = t & 63, w = t >> 6;
    const int lr = lane & 15, lg = lane >> 4;

    __shared__ int nbrL[64];                                   //   256 B
    __shared__ __align__(16) float geomL[64][4];               //  1024 B
    __shared__ __align__(16) unsigned short hidL[64 * 264];    // 33792 B (rows 0..15 reused as hbar)
    __shared__ float attnL[64][NHH];                           //  1024 B
    __shared__ unsigned short vbarL[16 * 72];                  //  2304 B
    // total 38400 B

    // ---- early register loads (latency overlapped with phase a/b) ----
    float qab[4][4];      // QA[pt0+mi][w*64+ni*16+lr] + b_u[...]
    float wa2v[4];
    #pragma unroll
    for (int ni = 0; ni < 4; ++ni) {
        const int c = w * 64 + ni * 16 + lr;
        wa2v[ni] = Wa2[ni * 16 + lr];
        const float bu = b_u[c];
        #pragma unroll
        for (int mi = 0; mi < 4; ++mi)
            qab[mi][ni] = bf2f(QAbf[(size_t)(pt0 + mi) * CC + c]) + bu;
    }

    // ---- phase a: indices + geometry ----
    if (t < 64) {
        const int g = t >> 4, k = t & 15;
        const int nb = idx[(size_t)(pt0 + g) * KK + k];
        nbrL[t] = nb;
        const float* Pb = P + (size_t)b * 3 * NN;
        const int nc = n0 + g;
        const float rx = Pb[nb] - Pb[nc];
        const float ry = Pb[NN + nb] - Pb[NN + nc];
        const float rz = Pb[2 * NN + nb] - Pb[2 * NN + nc];
        const float d = sqrtf(rx * rx + ry * ry + rz * rz);
        geomL[t][0] = rx; geomL[t][1] = ry; geomL[t][2] = rz; geomL[t][3] = d;
    }
    __syncthreads();

    // ---- KA prefetch (T14): issue all 64 gather loads now; consumed after
    //      the MFMA loop. Latency hides under phase b VALU + phase c MFMA. ----
    unsigned short ka[4][4][4];
    #pragma unroll
    for (int mi = 0; mi < 4; ++mi)
        #pragma unroll
        for (int reg = 0; reg < 4; ++reg) {
            const int r = mi * 16 + lg * 4 + reg;
            const size_t base = ((size_t)b * NN + nbrL[r]) * CC;
            #pragma unroll
            for (int ni = 0; ni < 4; ++ni)
                ka[mi][reg][ni] = KAbf[base + w * 64 + ni * 16 + lr];
        }

    // ---- phase b: hidden = relu(geom @ Wp1 + bp1), bf16 in LDS ----
    {
        const int c = t;
        const float w0 = Wp1[c], w1 = Wp1[CC + c], w2 = Wp1[2 * CC + c], w3 = Wp1[3 * CC + c];
        const float bb = bp1[c];
        #pragma unroll 4
        for (int r = 0; r < 64; ++r) {
            const float4 gm = *(const float4*)(&geomL[r][0]);
            float v = fmaf(gm.x, w0, fmaf(gm.y, w1, fmaf(gm.z, w2, fmaf(gm.w, w3, bb))));
            hidL[r * 264 + c] = f2bf(fmaxf(v, 0.f));
        }
    }
    __syncthreads();

    // ---- phase c: acc = qa+bu; acc += hidden @ Wpea (MFMA); logits; in-wave softmax ----
    f32x4 acc[4][4];
    #pragma unroll
    for (int mi = 0; mi < 4; ++mi)
        #pragma unroll
        for (int ni = 0; ni < 4; ++ni) {
            const float v = qab[mi][ni];
            acc[mi][ni] = (f32x4){v, v, v, v};
        }

    #pragma unroll
    for (int kk = 0; kk < 8; ++kk) {
        const int ko = kk * 32 + lg * 8;
        short8 a[4];
        #pragma unroll
        for (int mi = 0; mi < 4; ++mi)
            a[mi] = *(const short8*)(&hidL[(mi * 16 + lr) * 264 + ko]);
        #pragma unroll
        for (int ni = 0; ni < 4; ++ni) {
            const int col = w * 64 + ni * 16 + lr;
            short8 bfr = *(const short8*)(WpeaT + (size_t)col * CC + ko);
            #pragma unroll
            for (int mi = 0; mi < 4; ++mi)
                acc[mi][ni] = __builtin_amdgcn_mfma_f32_16x16x32_bf16(a[mi], bfr, acc[mi][ni], 0, 0, 0);
        }
    }

    // logits + softmax, fully within wave w (= head w); KA already in regs
    #pragma unroll
    for (int mi = 0; mi < 4; ++mi) {
        float pl[4];
        #pragma unroll
        for (int reg = 0; reg < 4; ++reg) {
            float s = 0.f;
            #pragma unroll
            for (int ni = 0; ni < 4; ++ni) {
                const float u = acc[mi][ni][reg] - bf2f(ka[mi][reg][ni]);
                s += fmaxf(u, 0.f) * wa2v[ni];
            }
            s += __shfl_xor(s, 1);
            s += __shfl_xor(s, 2);
            s += __shfl_xor(s, 4);
            s += __shfl_xor(s, 8);
            pl[reg] = s;   // logit for (point mi, k = lg*4+reg); same across lr
        }
        // softmax over k = (lg,reg): reduce across regs then lg lanes (xor 16,32)
        float m = fmaxf(fmaxf(pl[0], pl[1]), fmaxf(pl[2], pl[3]));
        m = fmaxf(m, __shfl_xor(m, 16));
        m = fmaxf(m, __shfl_xor(m, 32));
        float e[4], s = 0.f;
        #pragma unroll
        for (int reg = 0; reg < 4; ++reg) { e[reg] = __expf(pl[reg] - m); s += e[reg]; }
        s += __shfl_xor(s, 16);
        s += __shfl_xor(s, 32);
        const float inv = 1.f / s;
        if (lr == 0) {
            #pragma unroll
            for (int reg = 0; reg < 4; ++reg)
                attnL[mi * 16 + lg * 4 + reg][w] = e[reg] * inv;
        }
    }

    // ---- V prefetch (T14): KA regs are dead now; issue all 64 V loads,
    //      covered by the softmax barrier + hbar reduction below. ----
    unsigned short vv[4][16];
    #pragma unroll
    for (int i = 0; i < 4; ++i) {
        const int gh = w * 4 + i;
        const int g = gh >> 2, hh = gh & 3;
        #pragma unroll
        for (int k = 0; k < 16; ++k) {
            const int r = g * 16 + k;
            vv[i][k] = Vbf[((size_t)b * NN + nbrL[r]) * CC + hh * 64 + lane];
        }
    }
    __syncthreads();

    // ---- phase e: hbar = sum_k attn*hidden -> aliased into hidL rows 0..15;
    //              vbar = sum_k attn*V (from prefetched regs) -> vbarL ----
    {
        const int c = t;   // this thread owns column c of hidL exclusively
        #pragma unroll
        for (int g = 0; g < 4; ++g) {
            float hv[16];
            #pragma unroll
            for (int k = 0; k < 16; ++k) hv[k] = bf2f(hidL[(g * 16 + k) * 264 + c]);
            #pragma unroll
            for (int hh = 0; hh < NHH; ++hh) {
                float s = 0.f;
                #pragma unroll
                for (int k = 0; k < 16; ++k) s += attnL[g * 16 + k][hh] * hv[k];
                hidL[(g * 4 + hh) * 264 + c] = f2bf(s);   // hbar row g*4+hh
            }
        }
    }
    {
        #pragma unroll
        for (int i = 0; i < 4; ++i) {
            const int gh = w * 4 + i;
            const int g = gh >> 2, hh = gh & 3;
            float s = 0.f;
            #pragma unroll
            for (int k = 0; k < 16; ++k)
                s += attnL[g * 16 + k][hh] * bf2f(vv[i][k]);
            vbarL[gh * 72 + lane] = f2bf(s);
        }
    }
    __syncthreads();

    // ---- phase f: pe_agg = hbar @ Wp2 (head cols) via MFMA; agg out ----
    f32x4 acc2[4];
    #pragma unroll
    for (int ni = 0; ni < 4; ++ni) acc2[ni] = (f32x4){0.f, 0.f, 0.f, 0.f};
    #pragma unroll
    for (int kk = 0; kk < 8; ++kk) {
        const int ko = kk * 32 + lg * 8;
        short8 a = *(const short8*)(&hidL[lr * 264 + ko]);   // hbar row lr
        #pragma unroll
        for (int ni = 0; ni < 4; ++ni) {
            const int col = w * 64 + ni * 16 + lr;
            short8 bfr = *(const short8*)(Wp2T + (size_t)col * CC + ko);
            acc2[ni] = __builtin_amdgcn_mfma_f32_16x16x32_bf16(a, bfr, acc2[ni], 0, 0, 0);
        }
    }
    #pragma unroll
    for (int ni = 0; ni < 4; ++ni) {
        const int cl = ni * 16 + lr;
        const int c = w * 64 + cl;
        // output row = lg*4 + reg; rows with hh == w  <=>  reg == w.
        float pv;
        if      (w == 0) pv = acc2[ni][0];
        else if (w == 1) pv = acc2[ni][1];
        else if (w == 2) pv = acc2[ni][2];
        else             pv = acc2[ni][3];
        const float v = pv + bf2f(vbarL[(lg * 4 + w) * 72 + cl]) + bp2[c];
        aggbf[(size_t)(pt0 + lg) * CC + c] = f2bf(v);
    }
}

// ---------------------------------------------------------------------------
extern "C" void kernel_launch(void* const* d_in, const int* in_sizes, int n_in,
                              void* d_out, int out_size, void* d_ws, size_t ws_size,
                              hipStream_t stream)
{
    const float* h   = (const float*)d_in[0];
    const float* P   = (const float*)d_in[1];
    const int*   idx = (const int*)d_in[2];
    const float* Wq  = (const float*)d_in[3];
    const float* Wk  = (const float*)d_in[4];
    const float* Wv  = (const float*)d_in[5];
    const float* Wp1 = (const float*)d_in[6];
    const float* bp1 = (const float*)d_in[7];
    const float* Wp2 = (const float*)d_in[8];
    const float* bp2 = (const float*)d_in[9];
    const float* Wa1 = (const float*)d_in[10];
    const float* ba1 = (const float*)d_in[11];
    const float* Wa2 = (const float*)d_in[12];
    const float* Wo  = (const float*)d_in[14];
    const float* bo  = (const float*)d_in[15];

    char* ws = (char*)d_ws;
    const size_t MB16 = 16777216;   // BN*CC*2 bytes
    unsigned short* WqaT  = (unsigned short*)(ws + 0);
    unsigned short* WkaT  = (unsigned short*)(ws + 131072);
    unsigned short* WvT   = (unsigned short*)(ws + 262144);
    unsigned short* WpeaT = (unsigned short*)(ws + 393216);
    unsigned short* Wp2T  = (unsigned short*)(ws + 524288);
    unsigned short* WoT   = (unsigned short*)(ws + 655360);
    float*          b_u   = (float*)(ws + 786432);
    const size_t base = 1 << 20;
    unsigned short* hbf   = (unsigned short*)(ws + base + 0 * MB16);
    unsigned short* QAbf  = (unsigned short*)(ws + base + 1 * MB16);
    unsigned short* KAbf  = (unsigned short*)(ws + base + 2 * MB16);
    unsigned short* Vbf   = (unsigned short*)(ws + base + 3 * MB16);
    unsigned short* aggbf = (unsigned short*)(ws + base + 4 * MB16);
    if (ws_size < base + 5 * MB16) return;   // insufficient scratch -> fail loudly

    prep_kernel<<<dim3(256, 7), 256, 0, stream>>>(Wq, Wk, Wv, Wp2, Wo, Wa1, bp2, ba1,
                                                  WqaT, WkaT, WvT, WpeaT, Wp2T, WoT, b_u);
    h2bf_kernel<<<BN * CC / 4 / 256, 256, 0, stream>>>(h, hbf);
    gemm64_kernel<false><<<dim3(BN / 64, 3), 256, 0, stream>>>(
        hbf, WqaT, WkaT, WvT, QAbf, KAbf, Vbf, nullptr, nullptr);
    fused_attn_kernel<<<BN / 4, 256, 0, stream>>>(P, idx, Wp1, bp1, Wa2, bp2,
                                                  QAbf, KAbf, Vbf, WpeaT, Wp2T, b_u, aggbf);
    gemm64_kernel<true><<<dim3(BN / 64, 1), 256, 0, stream>>>(
        aggbf, WoT, nullptr, nullptr, nullptr, nullptr, nullptr, (float*)d_out, bo);
}

// Round 6
// 410.194 us; speedup vs baseline: 1.2923x; 1.2923x over previous
//
#include <hip/hip_runtime.h>
#include <hip/hip_bf16.h>

#define BB 2
#define NN 16384
#define KK 16
#define CC 256
#define NHH 4
#define HDD 64
#define BN (BB*NN)   // 32768

typedef __attribute__((ext_vector_type(8))) short short8;
typedef __attribute__((ext_vector_type(4))) float f32x4;

__device__ __forceinline__ float bf2f(unsigned short u) {
    union { unsigned u32; float f; } x; x.u32 = ((unsigned)u) << 16; return x.f;
}
__device__ __forceinline__ unsigned short f2bf(float f) {
    union { float f; unsigned u; } x; x.f = f;
    unsigned r = x.u + 0x7FFFu + ((x.u >> 16) & 1u);
    return (unsigned short)(r >> 16);
}

// ---------------------------------------------------------------------------
// Prep: WqaT = (Wq @ blockdiag(Wa1))^T, WkaT, WpeaT likewise; plain transposes
// WvT, Wp2T, WoT; b_u = bp2 @ blockdiag(Wa1) + tile(ba1); Wp1aT[c][j]=Wp1[j][c]
// (j<4, zero-pad to 8) for the K=4 MFMA. grid (256, 7), 256 threads.
// ---------------------------------------------------------------------------
__global__ __launch_bounds__(256) void prep_kernel(
    const float* __restrict__ Wq, const float* __restrict__ Wk,
    const float* __restrict__ Wv, const float* __restrict__ Wp2,
    const float* __restrict__ Wo, const float* __restrict__ Wa1,
    const float* __restrict__ bp2, const float* __restrict__ ba1,
    const float* __restrict__ Wp1,
    unsigned short* WqaT, unsigned short* WkaT, unsigned short* WvT,
    unsigned short* WpeaT, unsigned short* Wp2T, unsigned short* WoT,
    float* b_u, unsigned short* Wp1aT)
{
    const int z = blockIdx.y;
    const int t = threadIdx.x;
    if (z < 3) {
        const float* W = (z == 0) ? Wq : (z == 1) ? Wk : Wp2;
        unsigned short* out = (z == 0) ? WqaT : (z == 1) ? WkaT : WpeaT;
        const int k = blockIdx.x;                 // row of W
        __shared__ float wrow[CC];
        __shared__ float a1[HDD * HDD];
        wrow[t] = W[k * CC + t];
        for (int i = t; i < HDD * HDD; i += 256) a1[i] = Wa1[i];
        __syncthreads();
        const int c = t;
        const int h0 = c & ~63;
        const int cl = c & 63;
        float s = 0.f;
        #pragma unroll 8
        for (int j = 0; j < HDD; ++j) s += wrow[h0 + j] * a1[j * HDD + cl];
        out[c * CC + k] = f2bf(s);
    } else if (z < 6) {
        const float* W = (z == 3) ? Wv : (z == 4) ? Wp2 : Wo;
        unsigned short* out = (z == 3) ? WvT : (z == 4) ? Wp2T : WoT;
        const int k = blockIdx.x;
        out[t * CC + k] = f2bf(W[k * CC + t]);
    } else {
        if (blockIdx.x == 0) {
            __shared__ float a1[HDD * HDD];
            for (int i = t; i < HDD * HDD; i += 256) a1[i] = Wa1[i];
            __syncthreads();
            const int c = t;
            const int h0 = c & ~63;
            const int cl = c & 63;
            float s = ba1[cl];
            #pragma unroll 8
            for (int j = 0; j < HDD; ++j) s += bp2[h0 + j] * a1[j * HDD + cl];
            b_u[c] = s;
        } else if (blockIdx.x == 1) {
            const int c = t;
            #pragma unroll
            for (int j = 0; j < 8; ++j)
                Wp1aT[c * 8 + j] = (j < 4) ? f2bf(Wp1[j * CC + c]) : (unsigned short)0;
        }
    }
}

// h (f32) -> hbf (bf16). grid 8192 x 256, 4 elems/thread.
__global__ __launch_bounds__(256) void h2bf_kernel(const float* __restrict__ h,
                                                   unsigned short* __restrict__ hbf)
{
    const int i = blockIdx.x * blockDim.x + threadIdx.x;
    const float4 v = ((const float4*)h)[i];
    ushort4 o;
    o.x = f2bf(v.x); o.y = f2bf(v.y); o.z = f2bf(v.z); o.w = f2bf(v.w);
    ((ushort4*)hbf)[i] = o;
}

// ---------------------------------------------------------------------------
// 64-row MFMA GEMM: D[m0:m0+64, 0:256] = A[m0:m0+64, :] @ B (B given as BT[col][k]).
// ---------------------------------------------------------------------------
template<bool FINAL>
__global__ __launch_bounds__(256) void gemm64_kernel(
    const unsigned short* __restrict__ A,
    const unsigned short* __restrict__ BT0, const unsigned short* __restrict__ BT1,
    const unsigned short* __restrict__ BT2,
    unsigned short* D0, unsigned short* D1, unsigned short* D2,
    float* Dout, const float* __restrict__ bias)
{
    const int m0 = blockIdx.x * 64;
    const unsigned short* BT;
    unsigned short* Dst = nullptr;
    if (!FINAL) {
        const int z = blockIdx.y;
        BT  = (z == 0) ? BT0 : (z == 1) ? BT1 : BT2;
        Dst = (z == 0) ? D0  : (z == 1) ? D1  : D2;
    } else {
        BT = BT0;
    }

    __shared__ __align__(16) unsigned short As[64 * 264];
    const int t = threadIdx.x;
    #pragma unroll
    for (int i = 0; i < 8; ++i) {
        const int flat = i * 2048 + t * 8;
        const int r = flat >> 8, c = flat & 255;
        short8 v = *(const short8*)(A + (size_t)(m0 + r) * CC + c);
        *(short8*)(&As[r * 264 + c]) = v;
    }
    __syncthreads();

    const int lane = t & 63, w = t >> 6;
    const int lr = lane & 15, lg = lane >> 4;

    f32x4 acc[4][4];
    #pragma unroll
    for (int mi = 0; mi < 4; ++mi)
        #pragma unroll
        for (int ni = 0; ni < 4; ++ni) acc[mi][ni] = (f32x4){0.f, 0.f, 0.f, 0.f};

    #pragma unroll
    for (int kk = 0; kk < 8; ++kk) {
        const int ko = kk * 32 + lg * 8;
        short8 a[4];
        #pragma unroll
        for (int mi = 0; mi < 4; ++mi)
            a[mi] = *(const short8*)(&As[(mi * 16 + lr) * 264 + ko]);
        #pragma unroll
        for (int ni = 0; ni < 4; ++ni) {
            const int col = w * 64 + ni * 16 + lr;
            short8 b = *(const short8*)(BT + (size_t)col * CC + ko);
            #pragma unroll
            for (int mi = 0; mi < 4; ++mi)
                acc[mi][ni] = __builtin_amdgcn_mfma_f32_16x16x32_bf16(a[mi], b, acc[mi][ni], 0, 0, 0);
        }
    }

    #pragma unroll
    for (int mi = 0; mi < 4; ++mi) {
        #pragma unroll
        for (int ni = 0; ni < 4; ++ni) {
            const int col = w * 64 + ni * 16 + lr;
            #pragma unroll
            for (int reg = 0; reg < 4; ++reg) {
                const int row = m0 + mi * 16 + lg * 4 + reg;
                const float v = acc[mi][ni][reg];
                if (FINAL) Dout[(size_t)row * CC + col] = v + bias[col];
                else       Dst[(size_t)row * CC + col] = f2bf(v);
            }
        }
    }
}

// ---------------------------------------------------------------------------
// Fused per-point attention. Block = 4 points x 16 neighbors = 64 rows,
// 256 threads (4 waves; wave w = head w). __launch_bounds__(256,3): r4 showed
// the 4-block reg cap starves gather ILP.
// r6: hidden-MLP and hbar converted from VALU to MFMA (K=4-padded and
// block-diag attn matmul). Gathers back at r3 placement (at-use; prefetch
// across barriers is drained by the compiler's vmcnt(0)-before-s_barrier).
// ---------------------------------------------------------------------------
__global__ __launch_bounds__(256, 3) void fused_attn_kernel(
    const float* __restrict__ P, const int* __restrict__ idx,
    const unsigned short* __restrict__ Wp1aT, const float* __restrict__ bp1,
    const float* __restrict__ Wa2, const float* __restrict__ bp2,
    const unsigned short* __restrict__ QAbf, const unsigned short* __restrict__ KAbf,
    const unsigned short* __restrict__ Vbf,  const unsigned short* __restrict__ WpeaT,
    const unsigned short* __restrict__ Wp2T, const float* __restrict__ b_u,
    unsigned short* __restrict__ aggbf)
{
    const int pt0 = blockIdx.x * 4;
    const int b = pt0 >> 14;          // pt0 / NN
    const int n0 = pt0 & (NN - 1);
    const int t = threadIdx.x;
    const int lane = t & 63, w = t >> 6;
    const int lr = lane & 15, lg = lane >> 4;

    __shared__ int nbrL[64];                                   //   256 B
    __shared__ __align__(16) unsigned short geomP[64 * 8];     //  1024 B (bf16, K-pad 8)
    __shared__ __align__(16) unsigned short hidL[64 * 264];    // 33792 B (rows 0..15 reused as hbar)
    __shared__ __align__(16) unsigned short attnA[16 * 72];    //  2304 B (block-diag attn, bf16)
    __shared__ unsigned short vbarL[16 * 72];                  //  2304 B
    // total 39680 B

    const short8 zero8 = {0, 0, 0, 0, 0, 0, 0, 0};

    // ---- early register loads (drained at first barrier; cheap) ----
    float qab[4][4];      // QA[pt0+mi][w*64+ni*16+lr] + b_u[...]
    float wa2v[4], bp1v[4];
    #pragma unroll
    for (int ni = 0; ni < 4; ++ni) {
        const int c = w * 64 + ni * 16 + lr;
        wa2v[ni] = Wa2[ni * 16 + lr];
        bp1v[ni] = bp1[c];
        const float bu = b_u[c];
        #pragma unroll
        for (int mi = 0; mi < 4; ++mi)
            qab[mi][ni] = bf2f(QAbf[(size_t)(pt0 + mi) * CC + c]) + bu;
    }

    // ---- phase a: indices + geometry (bf16, K-padded) + zero attnA ----
    for (int i = t; i < 576; i += 256) ((unsigned*)attnA)[i] = 0;
    if (t < 64) {
        const int g = t >> 4, k = t & 15;
        const int nb = idx[(size_t)(pt0 + g) * KK + k];
        nbrL[t] = nb;
        const float* Pb = P + (size_t)b * 3 * NN;
        const int nc = n0 + g;
        const float rx = Pb[nb] - Pb[nc];
        const float ry = Pb[NN + nb] - Pb[NN + nc];
        const float rz = Pb[2 * NN + nb] - Pb[2 * NN + nc];
        const float d = sqrtf(rx * rx + ry * ry + rz * rz);
        short8 gp = {(short)f2bf(rx), (short)f2bf(ry), (short)f2bf(rz), (short)f2bf(d),
                     0, 0, 0, 0};
        *(short8*)(&geomP[t * 8]) = gp;
    }
    __syncthreads();

    // ---- phase b: hidden = relu(geom @ Wp1 + bp1) via K=4-padded MFMA ----
    {
        short8 bb[4];
        #pragma unroll
        for (int ni = 0; ni < 4; ++ni) {
            const int col = w * 64 + ni * 16 + lr;
            bb[ni] = (lg == 0) ? *(const short8*)(Wp1aT + col * 8) : zero8;
        }
        #pragma unroll
        for (int mi = 0; mi < 4; ++mi) {
            short8 ag = (lg == 0) ? *(const short8*)(&geomP[(mi * 16 + lr) * 8]) : zero8;
            #pragma unroll
            for (int ni = 0; ni < 4; ++ni) {
                f32x4 ah = (f32x4){bp1v[ni], bp1v[ni], bp1v[ni], bp1v[ni]};
                ah = __builtin_amdgcn_mfma_f32_16x16x32_bf16(ag, bb[ni], ah, 0, 0, 0);
                const int col = w * 64 + ni * 16 + lr;
                #pragma unroll
                for (int reg = 0; reg < 4; ++reg)
                    hidL[(mi * 16 + lg * 4 + reg) * 264 + col] = f2bf(fmaxf(ah[reg], 0.f));
            }
        }
    }
    __syncthreads();

    // ---- phase c: acc = qa+bu; acc += hidden @ Wpea (MFMA); logits; in-wave softmax ----
    f32x4 acc[4][4];
    #pragma unroll
    for (int mi = 0; mi < 4; ++mi)
        #pragma unroll
        for (int ni = 0; ni < 4; ++ni) {
            const float v = qab[mi][ni];
            acc[mi][ni] = (f32x4){v, v, v, v};
        }

    #pragma unroll
    for (int kk = 0; kk < 8; ++kk) {
        const int ko = kk * 32 + lg * 8;
        short8 a[4];
        #pragma unroll
        for (int mi = 0; mi < 4; ++mi)
            a[mi] = *(const short8*)(&hidL[(mi * 16 + lr) * 264 + ko]);
        #pragma unroll
        for (int ni = 0; ni < 4; ++ni) {
            const int col = w * 64 + ni * 16 + lr;
            short8 bfr = *(const short8*)(WpeaT + (size_t)col * CC + ko);
            #pragma unroll
            for (int mi = 0; mi < 4; ++mi)
                acc[mi][ni] = __builtin_amdgcn_mfma_f32_16x16x32_bf16(a[mi], bfr, acc[mi][ni], 0, 0, 0);
        }
    }

    // logits + softmax, fully within wave w (= head w); KA loaded per-mi at use
    // (r3 placement -- interleaves gather latency with shuffle/VALU work).
    #pragma unroll
    for (int mi = 0; mi < 4; ++mi) {
        unsigned short ka[4][4];
        #pragma unroll
        for (int reg = 0; reg < 4; ++reg) {
            const int r = mi * 16 + lg * 4 + reg;
            const size_t base = ((size_t)b * NN + nbrL[r]) * CC;
            #pragma unroll
            for (int ni = 0; ni < 4; ++ni)
                ka[reg][ni] = KAbf[base + w * 64 + ni * 16 + lr];
        }
        float pl[4];
        #pragma unroll
        for (int reg = 0; reg < 4; ++reg) {
            float s = 0.f;
            #pragma unroll
            for (int ni = 0; ni < 4; ++ni) {
                const float u = acc[mi][ni][reg] - bf2f(ka[reg][ni]);
                s += fmaxf(u, 0.f) * wa2v[ni];
            }
            s += __shfl_xor(s, 1);
            s += __shfl_xor(s, 2);
            s += __shfl_xor(s, 4);
            s += __shfl_xor(s, 8);
            pl[reg] = s;   // logit for (point mi, k = lg*4+reg); same across lr
        }
        float m = fmaxf(fmaxf(pl[0], pl[1]), fmaxf(pl[2], pl[3]));
        m = fmaxf(m, __shfl_xor(m, 16));
        m = fmaxf(m, __shfl_xor(m, 32));
        float e[4], s = 0.f;
        #pragma unroll
        for (int reg = 0; reg < 4; ++reg) { e[reg] = __expf(pl[reg] - m); s += e[reg]; }
        s += __shfl_xor(s, 16);
        s += __shfl_xor(s, 32);
        const float inv = 1.f / s;
        if (lr == 0) {
            #pragma unroll
            for (int reg = 0; reg < 4; ++reg)
                attnA[(mi * 4 + w) * 72 + mi * 16 + lg * 4 + reg] = f2bf(e[reg] * inv);
        }
    }
    __syncthreads();

    // ---- phase e: issue V loads (FIFO-clean: hbar-MFMA below is LDS-only),
    //      hbar = attnA[16x64] @ hidL[64x256] via MFMA (written into hidL rows
    //      0..15, wave-private columns), then vbar from the landed V regs. ----
    unsigned short vv[4][16];
    #pragma unroll
    for (int i = 0; i < 4; ++i) {
        const int gh = w * 4 + i;
        const int g = gh >> 2, hh = gh & 3;
        #pragma unroll
        for (int k = 0; k < 16; ++k) {
            const int r = g * 16 + k;
            vv[i][k] = Vbf[((size_t)b * NN + nbrL[r]) * CC + hh * 64 + lane];
        }
    }

    #pragma unroll
    for (int ni = 0; ni < 4; ++ni) {
        const int colAbs = w * 64 + ni * 16 + lr;
        f32x4 ab = (f32x4){0.f, 0.f, 0.f, 0.f};
        #pragma unroll
        for (int kk = 0; kk < 2; ++kk) {
            short8 aa = *(const short8*)(&attnA[lr * 72 + kk * 32 + lg * 8]);
            short8 hb;
            #pragma unroll
            for (int j = 0; j < 8; ++j)
                hb[j] = (short)hidL[(kk * 32 + lg * 8 + j) * 264 + colAbs];
            ab = __builtin_amdgcn_mfma_f32_16x16x32_bf16(aa, hb, ab, 0, 0, 0);
        }
        #pragma unroll
        for (int reg = 0; reg < 4; ++reg)
            hidL[(lg * 4 + reg) * 264 + colAbs] = f2bf(ab[reg]);   // hbar row lg*4+reg
    }

    {
        #pragma unroll
        for (int i = 0; i < 4; ++i) {
            const int gh = w * 4 + i;
            const int g = gh >> 2;
            float s = 0.f;
            #pragma unroll
            for (int k = 0; k < 16; ++k)
                s += bf2f(attnA[gh * 72 + g * 16 + k]) * bf2f(vv[i][k]);
            vbarL[gh * 72 + lane] = f2bf(s);
        }
    }
    __syncthreads();

    // ---- phase f: pe_agg = hbar @ Wp2 (head cols) via MFMA; agg out ----
    f32x4 acc2[4];
    #pragma unroll
    for (int ni = 0; ni < 4; ++ni) acc2[ni] = (f32x4){0.f, 0.f, 0.f, 0.f};
    #pragma unroll
    for (int kk = 0; kk < 8; ++kk) {
        const int ko = kk * 32 + lg * 8;
        short8 a = *(const short8*)(&hidL[lr * 264 + ko]);   // hbar row lr
        #pragma unroll
        for (int ni = 0; ni < 4; ++ni) {
            const int col = w * 64 + ni * 16 + lr;
            short8 bfr = *(const short8*)(Wp2T + (size_t)col * CC + ko);
            acc2[ni] = __builtin_amdgcn_mfma_f32_16x16x32_bf16(a, bfr, acc2[ni], 0, 0, 0);
        }
    }
    #pragma unroll
    for (int ni = 0; ni < 4; ++ni) {
        const int cl = ni * 16 + lr;
        const int c = w * 64 + cl;
        // output row = lg*4 + reg; rows with hh == w  <=>  reg == w.
        float pv;
        if      (w == 0) pv = acc2[ni][0];
        else if (w == 1) pv = acc2[ni][1];
        else if (w == 2) pv = acc2[ni][2];
        else             pv = acc2[ni][3];
        const float v = pv + bf2f(vbarL[(lg * 4 + w) * 72 + cl]) + bp2[c];
        aggbf[(size_t)(pt0 + lg) * CC + c] = f2bf(v);
    }
}

// ---------------------------------------------------------------------------
extern "C" void kernel_launch(void* const* d_in, const int* in_sizes, int n_in,
                              void* d_out, int out_size, void* d_ws, size_t ws_size,
                              hipStream_t stream)
{
    const float* h   = (const float*)d_in[0];
    const float* P   = (const float*)d_in[1];
    const int*   idx = (const int*)d_in[2];
    const float* Wq  = (const float*)d_in[3];
    const float* Wk  = (const float*)d_in[4];
    const float* Wv  = (const float*)d_in[5];
    const float* Wp1 = (const float*)d_in[6];
    const float* bp1 = (const float*)d_in[7];
    const float* Wp2 = (const float*)d_in[8];
    const float* bp2 = (const float*)d_in[9];
    const float* Wa1 = (const float*)d_in[10];
    const float* ba1 = (const float*)d_in[11];
    const float* Wa2 = (const float*)d_in[12];
    const float* Wo  = (const float*)d_in[14];
    const float* bo  = (const float*)d_in[15];

    char* ws = (char*)d_ws;
    const size_t MB16 = 16777216;   // BN*CC*2 bytes
    unsigned short* WqaT  = (unsigned short*)(ws + 0);
    unsigned short* WkaT  = (unsigned short*)(ws + 131072);
    unsigned short* WvT   = (unsigned short*)(ws + 262144);
    unsigned short* WpeaT = (unsigned short*)(ws + 393216);
    unsigned short* Wp2T  = (unsigned short*)(ws + 524288);
    unsigned short* WoT   = (unsigned short*)(ws + 655360);
    float*          b_u   = (float*)(ws + 786432);
    unsigned short* Wp1aT = (unsigned short*)(ws + 787456);   // 2048 bf16 = 4 KB
    const size_t base = 1 << 20;
    unsigned short* hbf   = (unsigned short*)(ws + base + 0 * MB16);
    unsigned short* QAbf  = (unsigned short*)(ws + base + 1 * MB16);
    unsigned short* KAbf  = (unsigned short*)(ws + base + 2 * MB16);
    unsigned short* Vbf   = (unsigned short*)(ws + base + 3 * MB16);
    unsigned short* aggbf = (unsigned short*)(ws + base + 4 * MB16);
    if (ws_size < base + 5 * MB16) return;   // insufficient scratch -> fail loudly

    prep_kernel<<<dim3(256, 7), 256, 0, stream>>>(Wq, Wk, Wv, Wp2, Wo, Wa1, bp2, ba1, Wp1,
                                                  WqaT, WkaT, WvT, WpeaT, Wp2T, WoT,
                                                  b_u, Wp1aT);
    h2bf_kernel<<<BN * CC / 4 / 256, 256, 0, stream>>>(h, hbf);
    gemm64_kernel<false><<<dim3(BN / 64, 3), 256, 0, stream>>>(
        hbf, WqaT, WkaT, WvT, QAbf, KAbf, Vbf, nullptr, nullptr);
    fused_attn_kernel<<<BN / 4, 256, 0, stream>>>(P, idx, Wp1aT, bp1, Wa2, bp2,
                                                  QAbf, KAbf, Vbf, WpeaT, Wp2T, b_u, aggbf);
    gemm64_kernel<true><<<dim3(BN / 64, 1), 256, 0, stream>>>(
        aggbf, WoT, nullptr, nullptr, nullptr, nullptr, nullptr, (float*)d_out, bo);
}

// Round 7
// 395.821 us; speedup vs baseline: 1.3393x; 1.0363x over previous
//
#include <hip/hip_runtime.h>
#include <hip/hip_bf16.h>

#define BB 2
#define NN 16384
#define KK 16
#define CC 256
#define NHH 4
#define HDD 64
#define BN (BB*NN)   // 32768
#define HP 260       // hid LDS pitch (ushorts): 520B rows, 8B aligned; row*8 stride
                     // ≡ 64 mod 128B -> lg-groups split banks (4-way max, vs 8-way at 264)

typedef __attribute__((ext_vector_type(8))) short short8;
typedef __attribute__((ext_vector_type(4))) short s4;
typedef __attribute__((ext_vector_type(4))) float f32x4;

__device__ __forceinline__ float bf2f(unsigned short u) {
    union { unsigned u32; float f; } x; x.u32 = ((unsigned)u) << 16; return x.f;
}
__device__ __forceinline__ unsigned short f2bf(float f) {
    union { float f; unsigned u; } x; x.f = f;
    unsigned r = x.u + 0x7FFFu + ((x.u >> 16) & 1u);
    return (unsigned short)(r >> 16);
}
// 16-bf16-byte load from 8B-aligned LDS (two ds_read_b64)
__device__ __forceinline__ short8 ld8_lds(const unsigned short* p) {
    s4 lo = *(const s4*)(p);
    s4 hi = *(const s4*)(p + 4);
    short8 r;
    r[0] = lo[0]; r[1] = lo[1]; r[2] = lo[2]; r[3] = lo[3];
    r[4] = hi[0]; r[5] = hi[1]; r[6] = hi[2]; r[7] = hi[3];
    return r;
}

// ---------------------------------------------------------------------------
// Prep: WqaT = (Wq @ blockdiag(Wa1))^T, WkaT, WpeaT likewise; plain transposes
// WvT, Wp2T, WoT; b_u = bp2 @ blockdiag(Wa1) + tile(ba1); Wp1aT[c][j]=Wp1[j][c]
// (j<4, zero-pad to 8) for the K=4 MFMA. grid (256, 7), 256 threads.
// ---------------------------------------------------------------------------
__global__ __launch_bounds__(256) void prep_kernel(
    const float* __restrict__ Wq, const float* __restrict__ Wk,
    const float* __restrict__ Wv, const float* __restrict__ Wp2,
    const float* __restrict__ Wo, const float* __restrict__ Wa1,
    const float* __restrict__ bp2, const float* __restrict__ ba1,
    const float* __restrict__ Wp1,
    unsigned short* WqaT, unsigned short* WkaT, unsigned short* WvT,
    unsigned short* WpeaT, unsigned short* Wp2T, unsigned short* WoT,
    float* b_u, unsigned short* Wp1aT)
{
    const int z = blockIdx.y;
    const int t = threadIdx.x;
    if (z < 3) {
        const float* W = (z == 0) ? Wq : (z == 1) ? Wk : Wp2;
        unsigned short* out = (z == 0) ? WqaT : (z == 1) ? WkaT : WpeaT;
        const int k = blockIdx.x;                 // row of W
        __shared__ float wrow[CC];
        __shared__ float a1[HDD * HDD];
        wrow[t] = W[k * CC + t];
        for (int i = t; i < HDD * HDD; i += 256) a1[i] = Wa1[i];
        __syncthreads();
        const int c = t;
        const int h0 = c & ~63;
        const int cl = c & 63;
        float s = 0.f;
        #pragma unroll 8
        for (int j = 0; j < HDD; ++j) s += wrow[h0 + j] * a1[j * HDD + cl];
        out[c * CC + k] = f2bf(s);
    } else if (z < 6) {
        const float* W = (z == 3) ? Wv : (z == 4) ? Wp2 : Wo;
        unsigned short* out = (z == 3) ? WvT : (z == 4) ? Wp2T : WoT;
        const int k = blockIdx.x;
        out[t * CC + k] = f2bf(W[k * CC + t]);
    } else {
        if (blockIdx.x == 0) {
            __shared__ float a1[HDD * HDD];
            for (int i = t; i < HDD * HDD; i += 256) a1[i] = Wa1[i];
            __syncthreads();
            const int c = t;
            const int h0 = c & ~63;
            const int cl = c & 63;
            float s = ba1[cl];
            #pragma unroll 8
            for (int j = 0; j < HDD; ++j) s += bp2[h0 + j] * a1[j * HDD + cl];
            b_u[c] = s;
        } else if (blockIdx.x == 1) {
            const int c = t;
            #pragma unroll
            for (int j = 0; j < 8; ++j)
                Wp1aT[c * 8 + j] = (j < 4) ? f2bf(Wp1[j * CC + c]) : (unsigned short)0;
        }
    }
}

// h (f32) -> hbf (bf16). grid 8192 x 256, 4 elems/thread.
__global__ __launch_bounds__(256) void h2bf_kernel(const float* __restrict__ h,
                                                   unsigned short* __restrict__ hbf)
{
    const int i = blockIdx.x * blockDim.x + threadIdx.x;
    const float4 v = ((const float4*)h)[i];
    ushort4 o;
    o.x = f2bf(v.x); o.y = f2bf(v.y); o.z = f2bf(v.z); o.w = f2bf(v.w);
    ((ushort4*)hbf)[i] = o;
}

// ---------------------------------------------------------------------------
// 64-row MFMA GEMM: D[m0:m0+64, 0:256] = A[m0:m0+64, :] @ B (B given as BT[col][k]).
// ---------------------------------------------------------------------------
template<bool FINAL>
__global__ __launch_bounds__(256) void gemm64_kernel(
    const unsigned short* __restrict__ A,
    const unsigned short* __restrict__ BT0, const unsigned short* __restrict__ BT1,
    const unsigned short* __restrict__ BT2,
    unsigned short* D0, unsigned short* D1, unsigned short* D2,
    float* Dout, const float* __restrict__ bias)
{
    const int m0 = blockIdx.x * 64;
    const unsigned short* BT;
    unsigned short* Dst = nullptr;
    if (!FINAL) {
        const int z = blockIdx.y;
        BT  = (z == 0) ? BT0 : (z == 1) ? BT1 : BT2;
        Dst = (z == 0) ? D0  : (z == 1) ? D1  : D2;
    } else {
        BT = BT0;
    }

    __shared__ __align__(16) unsigned short As[64 * 264];
    const int t = threadIdx.x;
    #pragma unroll
    for (int i = 0; i < 8; ++i) {
        const int flat = i * 2048 + t * 8;
        const int r = flat >> 8, c = flat & 255;
        short8 v = *(const short8*)(A + (size_t)(m0 + r) * CC + c);
        *(short8*)(&As[r * 264 + c]) = v;
    }
    __syncthreads();

    const int lane = t & 63, w = t >> 6;
    const int lr = lane & 15, lg = lane >> 4;

    f32x4 acc[4][4];
    #pragma unroll
    for (int mi = 0; mi < 4; ++mi)
        #pragma unroll
        for (int ni = 0; ni < 4; ++ni) acc[mi][ni] = (f32x4){0.f, 0.f, 0.f, 0.f};

    #pragma unroll
    for (int kk = 0; kk < 8; ++kk) {
        const int ko = kk * 32 + lg * 8;
        short8 a[4];
        #pragma unroll
        for (int mi = 0; mi < 4; ++mi)
            a[mi] = *(const short8*)(&As[(mi * 16 + lr) * 264 + ko]);
        #pragma unroll
        for (int ni = 0; ni < 4; ++ni) {
            const int col = w * 64 + ni * 16 + lr;
            short8 b = *(const short8*)(BT + (size_t)col * CC + ko);
            #pragma unroll
            for (int mi = 0; mi < 4; ++mi)
                acc[mi][ni] = __builtin_amdgcn_mfma_f32_16x16x32_bf16(a[mi], b, acc[mi][ni], 0, 0, 0);
        }
    }

    #pragma unroll
    for (int mi = 0; mi < 4; ++mi) {
        #pragma unroll
        for (int ni = 0; ni < 4; ++ni) {
            const int col = w * 64 + ni * 16 + lr;
            #pragma unroll
            for (int reg = 0; reg < 4; ++reg) {
                const int row = m0 + mi * 16 + lg * 4 + reg;
                const float v = acc[mi][ni][reg];
                if (FINAL) Dout[(size_t)row * CC + col] = v + bias[col];
                else       Dst[(size_t)row * CC + col] = f2bf(v);
            }
        }
    }
}

// ---------------------------------------------------------------------------
// Fused per-point attention. Block = 4 points x 16 neighbors = 64 rows,
// 256 threads (4 waves; wave w = head w).
// r7: (1) __launch_bounds__(256,4) -- r6 code sits at 80 VGPR, well under the
// 128 cap, so 4 blocks/CU is pure TLP (r4's failure was a 64-reg squeeze of
// heavier code). LDS trimmed to 39168 B (4x fits in 160 KB).
// (2) hid pitch 264->260 (520B rows): row*8 stride = 64 mod 128B -> hbar
// B-column scalar reads drop 8-way->4-way; row*4 writes become conflict-free.
// A-fragments use 2x ds_read_b64 (8B-aligned rows) instead of b128.
// ---------------------------------------------------------------------------
__global__ __launch_bounds__(256, 4) void fused_attn_kernel(
    const float* __restrict__ P, const int* __restrict__ idx,
    const unsigned short* __restrict__ Wp1aT, const float* __restrict__ bp1,
    const float* __restrict__ Wa2, const float* __restrict__ bp2,
    const unsigned short* __restrict__ QAbf, const unsigned short* __restrict__ KAbf,
    const unsigned short* __restrict__ Vbf,  const unsigned short* __restrict__ WpeaT,
    const unsigned short* __restrict__ Wp2T, const float* __restrict__ b_u,
    unsigned short* __restrict__ aggbf)
{
    const int pt0 = blockIdx.x * 4;
    const int b = pt0 >> 14;          // pt0 / NN
    const int n0 = pt0 & (NN - 1);
    const int t = threadIdx.x;
    const int lane = t & 63, w = t >> 6;
    const int lr = lane & 15, lg = lane >> 4;

    __shared__ int nbrL[64];                                   //   256 B
    __shared__ __align__(16) unsigned short geomP[64 * 8];     //  1024 B (bf16, K-pad 8)
    __shared__ __align__(16) unsigned short hidL[64 * HP];     // 33280 B (rows 0..15 reused as hbar)
    __shared__ __align__(16) unsigned short attnA[16 * 72];    //  2304 B (block-diag attn, bf16)
    __shared__ unsigned short vbarL[16 * 72];                  //  2304 B
    // total 39168 B -> 4 blocks/CU

    const short8 zero8 = {0, 0, 0, 0, 0, 0, 0, 0};

    // ---- early register loads (drained at first barrier; cheap) ----
    float qab[4][4];      // QA[pt0+mi][w*64+ni*16+lr] + b_u[...]
    float wa2v[4], bp1v[4];
    #pragma unroll
    for (int ni = 0; ni < 4; ++ni) {
        const int c = w * 64 + ni * 16 + lr;
        wa2v[ni] = Wa2[ni * 16 + lr];
        bp1v[ni] = bp1[c];
        const float bu = b_u[c];
        #pragma unroll
        for (int mi = 0; mi < 4; ++mi)
            qab[mi][ni] = bf2f(QAbf[(size_t)(pt0 + mi) * CC + c]) + bu;
    }

    // ---- phase a: indices + geometry (bf16, K-padded) + zero attnA ----
    for (int i = t; i < 576; i += 256) ((unsigned*)attnA)[i] = 0;
    if (t < 64) {
        const int g = t >> 4, k = t & 15;
        const int nb = idx[(size_t)(pt0 + g) * KK + k];
        nbrL[t] = nb;
        const float* Pb = P + (size_t)b * 3 * NN;
        const int nc = n0 + g;
        const float rx = Pb[nb] - Pb[nc];
        const float ry = Pb[NN + nb] - Pb[NN + nc];
        const float rz = Pb[2 * NN + nb] - Pb[2 * NN + nc];
        const float d = sqrtf(rx * rx + ry * ry + rz * rz);
        short8 gp = {(short)f2bf(rx), (short)f2bf(ry), (short)f2bf(rz), (short)f2bf(d),
                     0, 0, 0, 0};
        *(short8*)(&geomP[t * 8]) = gp;
    }
    __syncthreads();

    // ---- phase b: hidden = relu(geom @ Wp1 + bp1) via K=4-padded MFMA ----
    {
        short8 bb[4];
        #pragma unroll
        for (int ni = 0; ni < 4; ++ni) {
            const int col = w * 64 + ni * 16 + lr;
            bb[ni] = (lg == 0) ? *(const short8*)(Wp1aT + col * 8) : zero8;
        }
        #pragma unroll
        for (int mi = 0; mi < 4; ++mi) {
            short8 ag = (lg == 0) ? *(const short8*)(&geomP[(mi * 16 + lr) * 8]) : zero8;
            #pragma unroll
            for (int ni = 0; ni < 4; ++ni) {
                f32x4 ah = (f32x4){bp1v[ni], bp1v[ni], bp1v[ni], bp1v[ni]};
                ah = __builtin_amdgcn_mfma_f32_16x16x32_bf16(ag, bb[ni], ah, 0, 0, 0);
                const int col = w * 64 + ni * 16 + lr;
                #pragma unroll
                for (int reg = 0; reg < 4; ++reg)
                    hidL[(mi * 16 + lg * 4 + reg) * HP + col] = f2bf(fmaxf(ah[reg], 0.f));
            }
        }
    }
    __syncthreads();

    // ---- phase c: acc = qa+bu; acc += hidden @ Wpea (MFMA); logits; in-wave softmax ----
    f32x4 acc[4][4];
    #pragma unroll
    for (int mi = 0; mi < 4; ++mi)
        #pragma unroll
        for (int ni = 0; ni < 4; ++ni) {
            const float v = qab[mi][ni];
            acc[mi][ni] = (f32x4){v, v, v, v};
        }

    #pragma unroll
    for (int kk = 0; kk < 8; ++kk) {
        const int ko = kk * 32 + lg * 8;
        short8 a[4];
        #pragma unroll
        for (int mi = 0; mi < 4; ++mi)
            a[mi] = ld8_lds(&hidL[(mi * 16 + lr) * HP + ko]);
        #pragma unroll
        for (int ni = 0; ni < 4; ++ni) {
            const int col = w * 64 + ni * 16 + lr;
            short8 bfr = *(const short8*)(WpeaT + (size_t)col * CC + ko);
            #pragma unroll
            for (int mi = 0; mi < 4; ++mi)
                acc[mi][ni] = __builtin_amdgcn_mfma_f32_16x16x32_bf16(a[mi], bfr, acc[mi][ni], 0, 0, 0);
        }
    }

    // logits + softmax, fully within wave w (= head w); KA loaded per-mi at use
    // (r3 placement -- interleaves gather latency with shuffle/VALU work).
    #pragma unroll
    for (int mi = 0; mi < 4; ++mi) {
        unsigned short ka[4][4];
        #pragma unroll
        for (int reg = 0; reg < 4; ++reg) {
            const int r = mi * 16 + lg * 4 + reg;
            const size_t base = ((size_t)b * NN + nbrL[r]) * CC;
            #pragma unroll
            for (int ni = 0; ni < 4; ++ni)
                ka[reg][ni] = KAbf[base + w * 64 + ni * 16 + lr];
        }
        float pl[4];
        #pragma unroll
        for (int reg = 0; reg < 4; ++reg) {
            float s = 0.f;
            #pragma unroll
            for (int ni = 0; ni < 4; ++ni) {
                const float u = acc[mi][ni][reg] - bf2f(ka[reg][ni]);
                s += fmaxf(u, 0.f) * wa2v[ni];
            }
            s += __shfl_xor(s, 1);
            s += __shfl_xor(s, 2);
            s += __shfl_xor(s, 4);
            s += __shfl_xor(s, 8);
            pl[reg] = s;   // logit for (point mi, k = lg*4+reg); same across lr
        }
        float m = fmaxf(fmaxf(pl[0], pl[1]), fmaxf(pl[2], pl[3]));
        m = fmaxf(m, __shfl_xor(m, 16));
        m = fmaxf(m, __shfl_xor(m, 32));
        float e[4], s = 0.f;
        #pragma unroll
        for (int reg = 0; reg < 4; ++reg) { e[reg] = __expf(pl[reg] - m); s += e[reg]; }
        s += __shfl_xor(s, 16);
        s += __shfl_xor(s, 32);
        const float inv = 1.f / s;
        if (lr == 0) {
            #pragma unroll
            for (int reg = 0; reg < 4; ++reg)
                attnA[(mi * 4 + w) * 72 + mi * 16 + lg * 4 + reg] = f2bf(e[reg] * inv);
        }
    }
    __syncthreads();

    // ---- phase e: issue V loads (FIFO-clean: hbar-MFMA below is LDS-only),
    //      hbar = attnA[16x64] @ hidL[64x256] via MFMA (written into hidL rows
    //      0..15, wave-private columns), then vbar from the landed V regs. ----
    unsigned short vv[4][16];
    #pragma unroll
    for (int i = 0; i < 4; ++i) {
        const int gh = w * 4 + i;
        const int g = gh >> 2, hh = gh & 3;
        #pragma unroll
        for (int k = 0; k < 16; ++k) {
            const int r = g * 16 + k;
            vv[i][k] = Vbf[((size_t)b * NN + nbrL[r]) * CC + hh * 64 + lane];
        }
    }

    #pragma unroll
    for (int ni = 0; ni < 4; ++ni) {
        const int colAbs = w * 64 + ni * 16 + lr;
        f32x4 ab = (f32x4){0.f, 0.f, 0.f, 0.f};
        #pragma unroll
        for (int kk = 0; kk < 2; ++kk) {
            short8 aa = ld8_lds(&attnA[lr * 72 + kk * 32 + lg * 8]);
            short8 hb;
            #pragma unroll
            for (int j = 0; j < 8; ++j)
                hb[j] = (short)hidL[(kk * 32 + lg * 8 + j) * HP + colAbs];
            ab = __builtin_amdgcn_mfma_f32_16x16x32_bf16(aa, hb, ab, 0, 0, 0);
        }
        #pragma unroll
        for (int reg = 0; reg < 4; ++reg)
            hidL[(lg * 4 + reg) * HP + colAbs] = f2bf(ab[reg]);   // hbar row lg*4+reg
    }

    {
        #pragma unroll
        for (int i = 0; i < 4; ++i) {
            const int gh = w * 4 + i;
            const int g = gh >> 2;
            float s = 0.f;
            #pragma unroll
            for (int k = 0; k < 16; ++k)
                s += bf2f(attnA[gh * 72 + g * 16 + k]) * bf2f(vv[i][k]);
            vbarL[gh * 72 + lane] = f2bf(s);
        }
    }
    __syncthreads();

    // ---- phase f: pe_agg = hbar @ Wp2 (head cols) via MFMA; agg out ----
    f32x4 acc2[4];
    #pragma unroll
    for (int ni = 0; ni < 4; ++ni) acc2[ni] = (f32x4){0.f, 0.f, 0.f, 0.f};
    #pragma unroll
    for (int kk = 0; kk < 8; ++kk) {
        const int ko = kk * 32 + lg * 8;
        short8 a = ld8_lds(&hidL[lr * HP + ko]);   // hbar row lr
        #pragma unroll
        for (int ni = 0; ni < 4; ++ni) {
            const int col = w * 64 + ni * 16 + lr;
            short8 bfr = *(const short8*)(Wp2T + (size_t)col * CC + ko);
            acc2[ni] = __builtin_amdgcn_mfma_f32_16x16x32_bf16(a, bfr, acc2[ni], 0, 0, 0);
        }
    }
    #pragma unroll
    for (int ni = 0; ni < 4; ++ni) {
        const int cl = ni * 16 + lr;
        const int c = w * 64 + cl;
        // output row = lg*4 + reg; rows with hh == w  <=>  reg == w.
        float pv;
        if      (w == 0) pv = acc2[ni][0];
        else if (w == 1) pv = acc2[ni][1];
        else if (w == 2) pv = acc2[ni][2];
        else             pv = acc2[ni][3];
        const float v = pv + bf2f(vbarL[(lg * 4 + w) * 72 + cl]) + bp2[c];
        aggbf[(size_t)(pt0 + lg) * CC + c] = f2bf(v);
    }
}

// ---------------------------------------------------------------------------
extern "C" void kernel_launch(void* const* d_in, const int* in_sizes, int n_in,
                              void* d_out, int out_size, void* d_ws, size_t ws_size,
                              hipStream_t stream)
{
    const float* h   = (const float*)d_in[0];
    const float* P   = (const float*)d_in[1];
    const int*   idx = (const int*)d_in[2];
    const float* Wq  = (const float*)d_in[3];
    const float* Wk  = (const float*)d_in[4];
    const float* Wv  = (const float*)d_in[5];
    const float* Wp1 = (const float*)d_in[6];
    const float* bp1 = (const float*)d_in[7];
    const float* Wp2 = (const float*)d_in[8];
    const float* bp2 = (const float*)d_in[9];
    const float* Wa1 = (const float*)d_in[10];
    const float* ba1 = (const float*)d_in[11];
    const float* Wa2 = (const float*)d_in[12];
    const float* Wo  = (const float*)d_in[14];
    const float* bo  = (const float*)d_in[15];

    char* ws = (char*)d_ws;
    const size_t MB16 = 16777216;   // BN*CC*2 bytes
    unsigned short* WqaT  = (unsigned short*)(ws + 0);
    unsigned short* WkaT  = (unsigned short*)(ws + 131072);
    unsigned short* WvT   = (unsigned short*)(ws + 262144);
    unsigned short* WpeaT = (unsigned short*)(ws + 393216);
    unsigned short* Wp2T  = (unsigned short*)(ws + 524288);
    unsigned short* WoT   = (unsigned short*)(ws + 655360);
    float*          b_u   = (float*)(ws + 786432);
    unsigned short* Wp1aT = (unsigned short*)(ws + 787456);   // 2048 bf16 = 4 KB
    const size_t base = 1 << 20;
    unsigned short* hbf   = (unsigned short*)(ws + base + 0 * MB16);
    unsigned short* QAbf  = (unsigned short*)(ws + base + 1 * MB16);
    unsigned short* KAbf  = (unsigned short*)(ws + base + 2 * MB16);
    unsigned short* Vbf   = (unsigned short*)(ws + base + 3 * MB16);
    unsigned short* aggbf = (unsigned short*)(ws + base + 4 * MB16);
    if (ws_size < base + 5 * MB16) return;   // insufficient scratch -> fail loudly

    prep_kernel<<<dim3(256, 7), 256, 0, stream>>>(Wq, Wk, Wv, Wp2, Wo, Wa1, bp2, ba1, Wp1,
                                                  WqaT, WkaT, WvT, WpeaT, Wp2T, WoT,
                                                  b_u, Wp1aT);
    h2bf_kernel<<<BN * CC / 4 / 256, 256, 0, stream>>>(h, hbf);
    gemm64_kernel<false><<<dim3(BN / 64, 3), 256, 0, stream>>>(
        hbf, WqaT, WkaT, WvT, QAbf, KAbf, Vbf, nullptr, nullptr);
    fused_attn_kernel<<<BN / 4, 256, 0, stream>>>(P, idx, Wp1aT, bp1, Wa2, bp2,
                                                  QAbf, KAbf, Vbf, WpeaT, Wp2T, b_u, aggbf);
    gemm64_kernel<true><<<dim3(BN / 64, 1), 256, 0, stream>>>(
        aggbf, WoT, nullptr, nullptr, nullptr, nullptr, nullptr, (float*)d_out, bo);
}